// Round 1
// baseline (116.009 us; speedup 1.0000x reference)
//
#include <hip/hip_runtime.h>
#include <math.h>

#define H 2048
#define W 2048
#define K 16
#define P 15
#define CH 16   // rows per vpass chunk
#define CW 256  // cols per hpass block

// ---- kernel 1: pattern total sum -> C,S ; floor(vectors) -> int offsets ----
__global__ void geneo_prep(const float* __restrict__ patterns,
                           const float* __restrict__ vectors,
                           float* __restrict__ consts,
                           int* __restrict__ offs) {
    __shared__ float red[256];
    int t = threadIdx.x;
    float s = 0.f;
    for (int idx = t; idx < K * P * P; idx += 256) s += patterns[idx];
    red[t] = s;
    __syncthreads();
    for (int w = 128; w > 0; w >>= 1) {
        if (t < w) red[t] += red[t + w];
        __syncthreads();
    }
    if (t == 0) {
        float total = red[0];
        float invpp = 1.0f / (float)(P * P);
        consts[0] = ((float)K - total * invpp) / (float)(K - 1); // C
        consts[1] = invpp / (float)(K - 1);                      // S
    }
    if (t < 2 * K) offs[t] = (int)floorf(vectors[t]);
}

// ---- kernel 2: vertical 15-row sliding sum (exclusive: rows [i-P, i-1]) ----
__global__ void geneo_vpass(const float* __restrict__ img,
                            float* __restrict__ tmp) {
    int j  = blockIdx.x * blockDim.x + threadIdx.x; // column
    int r0 = blockIdx.y * CH;
    float s = 0.f;
    for (int a = r0 - P; a < r0; ++a)
        if (a >= 0) s += img[a * W + j];
    #pragma unroll
    for (int ii = 0; ii < CH; ++ii) {
        int i = r0 + ii;
        tmp[i * W + j] = s;
        s += img[i * W + j];
        int rem = i - P;
        if (rem >= 0) s -= img[rem * W + j];
    }
}

// ---- kernel 3: horizontal 15-col sum via LDS (cols [j-P, j-1]) ----
__global__ void geneo_hpass(const float* __restrict__ tmp,
                            float* __restrict__ win) {
    __shared__ float lds[CW + P + 1];
    int i  = blockIdx.y;
    int j0 = blockIdx.x * CW;
    int t  = threadIdx.x;
    int jj = j0 - P + t;
    lds[t] = (jj >= 0) ? tmp[i * W + jj] : 0.f;
    if (t < P) {
        int jj2 = j0 - P + CW + t;
        lds[CW + t] = (jj2 < W) ? tmp[i * W + jj2] : 0.f;
    }
    __syncthreads();
    float s = 0.f;
    #pragma unroll
    for (int d = 0; d < P; ++d) s += lds[t + d];
    win[i * W + j0 + t] = s;
}

// ---- kernel 4: 16-way circular-shift gather-sum ----
__global__ void geneo_gather(const float* __restrict__ win,
                             const float* __restrict__ consts,
                             const int* __restrict__ offs,
                             float* __restrict__ out) {
    __shared__ int soff[2 * K];
    __shared__ float sc[2];
    int t = threadIdx.x;
    if (t < 2 * K) soff[t] = offs[t];
    if (t < 2) sc[t] = consts[t];
    __syncthreads();

    int j = blockIdx.x * blockDim.x + t;
    int i = blockIdx.y;
    float acc = 0.f;
    #pragma unroll
    for (int k = 0; k < K; ++k) {
        int ri = (i - soff[2 * k]) % H;     if (ri < 0) ri += H;
        int rj = (j - soff[2 * k + 1]) % W; if (rj < 0) rj += W;
        acc += win[ri * W + rj];
    }
    out[i * W + j] = sc[0] + sc[1] * acc;
}

extern "C" void kernel_launch(void* const* d_in, const int* in_sizes, int n_in,
                              void* d_out, int out_size, void* d_ws, size_t ws_size,
                              hipStream_t stream) {
    const float* x        = (const float*)d_in[0]; // (1,1,H,W)
    const float* patterns = (const float*)d_in[1]; // (K,P,P)
    const float* vectors  = (const float*)d_in[2]; // (K,2)
    float* out = (float*)d_out;

    float* tmp    = (float*)d_ws;        // H*W floats
    float* win    = tmp + H * W;         // H*W floats
    float* consts = win + H * W;         // 2 floats
    int*   offs   = (int*)(consts + 2);  // 2K ints

    geneo_prep<<<1, 256, 0, stream>>>(patterns, vectors, consts, offs);
    geneo_vpass<<<dim3(W / 256, H / CH), 256, 0, stream>>>(x, tmp);
    geneo_hpass<<<dim3(W / CW, H), 256, 0, stream>>>(tmp, win);
    geneo_gather<<<dim3(W / 256, H), 256, 0, stream>>>(win, consts, offs, out);
}

// Round 2
// 108.581 us; speedup vs baseline: 1.0684x; 1.0684x over previous
//
#include <hip/hip_runtime.h>
#include <math.h>

#define H 2048
#define W 2048
#define K 16
#define P 15
#define CH 16          // rows per vpass chunk
#define WP 2052        // win pitch: W + 4 replicated guard cols (for wrapped float4 reads)

typedef float v4 __attribute__((ext_vector_type(4)));
typedef v4 uv4 __attribute__((aligned(4)));   // dword-aligned vector load (legal on gfx950)

// ---- kernel 1: vertical 15-row sliding sum (rows [i-P, i-1]), float4 cols ----
__global__ void geneo_vpass(const float* __restrict__ img,
                            float* __restrict__ tmp) {
    int j  = (blockIdx.x * blockDim.x + threadIdx.x) * 4;  // 4 columns per thread
    int r0 = blockIdx.y * CH;
    v4 s = {0.f, 0.f, 0.f, 0.f};
    #pragma unroll
    for (int d = P; d >= 1; --d) {
        int a = r0 - d;
        if (a >= 0) s += *(const v4*)&img[a * W + j];
    }
    #pragma unroll
    for (int ii = 0; ii < CH; ++ii) {
        int i = r0 + ii;
        *(v4*)&tmp[i * W + j] = s;
        s += *(const v4*)&img[i * W + j];
        int rem = i - P;
        if (rem >= 0) s -= *(const v4*)&img[rem * W + j];
    }
}

// ---- kernel 2: horizontal 15-col sum (cols [j-P, j-1]) via LDS, 1024-col tiles ----
__global__ void geneo_hpass(const float* __restrict__ tmp,
                            float* __restrict__ win) {
    __shared__ float lds[1040];
    int i  = blockIdx.y;
    int j0 = blockIdx.x * 1024;
    int t  = threadIdx.x;

    // load cols [j0-16, j0+1023] -> lds[0..1039]
    {
        int g = j0 - 16 + 4 * t;
        v4 v = (g >= 0) ? *(const v4*)&tmp[i * W + g] : (v4){0.f, 0.f, 0.f, 0.f};
        *(v4*)&lds[4 * t] = v;
        if (t < 4) {
            int g2 = j0 + 1008 + 4 * t;          // lds idx 1024+4t
            *(v4*)&lds[1024 + 4 * t] = *(const v4*)&tmp[i * W + g2];
        }
    }
    __syncthreads();

    int b = 4 * t + 1;                           // lds idx of col (j0+4t)-15
    float s0 = 0.f;
    #pragma unroll
    for (int m = 0; m < P; ++m) s0 += lds[b + m];
    float s1 = s0 - lds[b]     + lds[b + 15];
    float s2 = s1 - lds[b + 1] + lds[b + 16];
    float s3 = s2 - lds[b + 2] + lds[b + 17];
    v4 r = {s0, s1, s2, s3};
    *(v4*)&win[i * WP + j0 + 4 * t] = r;
    if (blockIdx.x == 0 && t == 0)               // guard cols 2048..2051 = cols 0..3
        *(v4*)&win[i * WP + W] = r;
}

// ---- kernel 3: fused consts + 16-way circular-shift gather-sum (float4) ----
__global__ void geneo_gather(const float* __restrict__ win,
                             const float* __restrict__ patterns,
                             const float* __restrict__ vectors,
                             float* __restrict__ out) {
    __shared__ float wsum[4];
    __shared__ int soy[K], sox[K];
    int t = threadIdx.x;

    // redundant per-block pattern total (3600 floats = 900 float4, L2-hot)
    float ps = 0.f;
    #pragma unroll
    for (int q = 0; q < 4; ++q) {
        int idx = t + q * 256;
        if (idx < 900) {
            v4 v = *(const v4*)&patterns[idx * 4];
            ps += (v.x + v.y) + (v.z + v.w);
        }
    }
    #pragma unroll
    for (int d = 32; d > 0; d >>= 1) ps += __shfl_down(ps, d, 64);
    if ((t & 63) == 0) wsum[t >> 6] = ps;
    if (t < K) {
        soy[t] = (int)floorf(vectors[2 * t]);
        sox[t] = (int)floorf(vectors[2 * t + 1]);
    }
    __syncthreads();

    float total = (wsum[0] + wsum[1]) + (wsum[2] + wsum[3]);
    const float invpp = 1.0f / 225.0f;
    float C = (16.0f - total * invpp) * (1.0f / 15.0f);
    const float S = invpp * (1.0f / 15.0f);      // 1/3375, data-independent

    int i = blockIdx.y;
    int j = (blockIdx.x * 256 + t) * 4;
    v4 acc = {0.f, 0.f, 0.f, 0.f};
    #pragma unroll
    for (int k = 0; k < K; ++k) {
        int ri = (i - soy[k]) & (H - 1);         // exact circular mod (pow2)
        int rj = (j - sox[k]) & (W - 1);
        acc += *(const uv4*)&win[ri * WP + rj];  // guard cols make wrapped f4 valid
    }
    v4 o = acc * S + C;
    *(v4*)&out[i * W + j] = o;
}

extern "C" void kernel_launch(void* const* d_in, const int* in_sizes, int n_in,
                              void* d_out, int out_size, void* d_ws, size_t ws_size,
                              hipStream_t stream) {
    const float* x        = (const float*)d_in[0]; // (1,1,H,W)
    const float* patterns = (const float*)d_in[1]; // (K,P,P)
    const float* vectors  = (const float*)d_in[2]; // (K,2)
    float* out = (float*)d_out;

    float* tmp = (float*)d_ws;                     // H*W floats
    float* win = tmp + H * W;                      // H*WP floats

    geneo_vpass<<<dim3(2, H / CH), 256, 0, stream>>>(x, tmp);
    geneo_hpass<<<dim3(2, H), 256, 0, stream>>>(tmp, win);
    geneo_gather<<<dim3(2, H), 256, 0, stream>>>(win, patterns, vectors, out);
}